// Round 1
// baseline (1525.158 us; speedup 1.0000x reference)
//
#include <hip/hip_runtime.h>
#include <hip/hip_bf16.h>
#include <math.h>

#define BB 4
#define WW 12
#define NN 1024
#define FIN 32
#define FOUT 32
#define HH 256
#define DD 32768     // N*FOUT
#define RR 48        // B*W
#define NCH 64       // k-chunks in projection

// ---------------- K1: d[r][i] = rsqrt(1 + sum_j shots[r][i][j]) ----------------
__global__ __launch_bounds__(256) void k_rowsum(const float* __restrict__ shots,
                                                float* __restrict__ d_arr) {
    int wave = (blockIdx.x * blockDim.x + threadIdx.x) >> 6;  // one wave per row
    int lane = threadIdx.x & 63;
    const float4* row = (const float4*)(shots + (size_t)wave * NN);
    float s = 0.f;
#pragma unroll
    for (int q = 0; q < 4; ++q) {
        float4 v = row[lane + q * 64];
        s += v.x + v.y + v.z + v.w;
    }
#pragma unroll
    for (int off = 32; off; off >>= 1) s += __shfl_xor(s, off, 64);
    if (lane == 0) d_arr[wave] = rsqrtf(s + 1.0f);
}

// ---------------- K2: tmp2[r][j][f] = d[r][j] * sum_k node[r][j][k]*gw[w][k][f] --
__global__ __launch_bounds__(256) void k_tmp2(const float* __restrict__ node,
                                              const float* __restrict__ gw,
                                              const float* __restrict__ d_arr,
                                              float* __restrict__ tmp2) {
    int r  = blockIdx.x >> 7;   // 0..47
    int jg = blockIdx.x & 127;  // 0..127
    int w  = r % WW;
    __shared__ float gwl[32 * 32];
#pragma unroll
    for (int q = 0; q < 4; ++q)
        gwl[threadIdx.x + q * 256] = gw[w * 1024 + threadIdx.x + q * 256];
    __syncthreads();
    int f  = threadIdx.x & 31;
    int jj = threadIdx.x >> 5;  // 0..7
    int j  = jg * 8 + jj;
    const float* nrow = node + ((size_t)r * NN + j) * FIN;
    float acc = 0.f;
#pragma unroll
    for (int k = 0; k < 32; ++k) acc = fmaf(nrow[k], gwl[k * 32 + f], acc);
    tmp2[((size_t)r * NN + j) * 32 + f] = d_arr[r * NN + j] * acc;
}

// ---------------- K3: x[w][b][i*32+f] = d[i]*(sum_j shots[i][j]*tmp2[j][f] + tmp2[i][f])
__global__ __launch_bounds__(512) void k_gcn(const float* __restrict__ shots,
                                             const float* __restrict__ tmp2,
                                             const float* __restrict__ d_arr,
                                             float* __restrict__ x) {
    int r  = blockIdx.x >> 3;   // 0..47  (= b*12 + w)
    int it = blockIdx.x & 7;    // 128-row tile
    int b  = r / WW, w = r % WW;
    int f  = threadIdx.x & 31;
    int rg = threadIdx.x >> 5;  // 0..15
    int i0 = it * 128 + rg * 8;
    const float*  t2    = tmp2 + (size_t)r * NN * 32;
    const float4* sbase = (const float4*)(shots + (size_t)r * NN * NN);
    float acc[8];
#pragma unroll
    for (int rr = 0; rr < 8; ++rr) acc[rr] = t2[(i0 + rr) * 32 + f];  // self-loop term
    const float* t2f = t2 + f;
    for (int j4 = 0; j4 < 256; ++j4) {
        float tv0 = t2f[(j4 * 4 + 0) * 32];
        float tv1 = t2f[(j4 * 4 + 1) * 32];
        float tv2 = t2f[(j4 * 4 + 2) * 32];
        float tv3 = t2f[(j4 * 4 + 3) * 32];
#pragma unroll
        for (int rr = 0; rr < 8; ++rr) {
            float4 a = sbase[(size_t)(i0 + rr) * 256 + j4];
            acc[rr] = fmaf(a.x, tv0, acc[rr]);
            acc[rr] = fmaf(a.y, tv1, acc[rr]);
            acc[rr] = fmaf(a.z, tv2, acc[rr]);
            acc[rr] = fmaf(a.w, tv3, acc[rr]);
        }
    }
    float* xout = x + ((size_t)w * BB + b) * DD;
#pragma unroll
    for (int rr = 0; rr < 8; ++rr) {
        int i = i0 + rr;
        xout[i * 32 + f] = d_arr[r * NN + i] * acc[rr];
    }
}

// ---------------- K4: partial[ch][s][c] = sum_{k in chunk} x[s][k]*w_ih[c][k] ----
__global__ __launch_bounds__(256) void k_proj(const float* __restrict__ x,
                                              const float* __restrict__ wih,
                                              float* __restrict__ partial) {
    int ct = blockIdx.x & 3;   // c-tile
    int ch = blockIdx.x >> 2;  // 0..63 k-chunk (512 k each)
    int c  = ct * 256 + threadIdx.x;
    const float4* wrow = (const float4*)(wih + (size_t)c * DD) + ch * 128;
    const float4* x4   = (const float4*)x + ch * 128;
    float acc[RR];
#pragma unroll
    for (int s = 0; s < RR; ++s) acc[s] = 0.f;
#pragma unroll 2
    for (int k4 = 0; k4 < 128; ++k4) {
        float4 wv = wrow[k4];
#pragma unroll
        for (int s = 0; s < RR; ++s) {
            float4 xv = x4[(size_t)s * (DD / 4) + k4];  // wave-uniform -> scalar cache
            acc[s] = fmaf(wv.x, xv.x, acc[s]);
            acc[s] = fmaf(wv.y, xv.y, acc[s]);
            acc[s] = fmaf(wv.z, xv.z, acc[s]);
            acc[s] = fmaf(wv.w, xv.w, acc[s]);
        }
    }
    float* pout = partial + (size_t)ch * (RR * 1024) + c;
#pragma unroll
    for (int s = 0; s < RR; ++s) pout[s * 1024] = acc[s];
}

// ---------------- K5: G[s][c] = sum_ch partial + biases ----------------
__global__ __launch_bounds__(256) void k_reduce(const float* __restrict__ partial,
                                                const float* __restrict__ bih,
                                                const float* __restrict__ bhh,
                                                float* __restrict__ G) {
    int idx = blockIdx.x * 256 + threadIdx.x;  // s*1024 + c
    float s = 0.f;
#pragma unroll 8
    for (int ch = 0; ch < NCH; ++ch) s += partial[(size_t)ch * (RR * 1024) + idx];
    int c = idx & 1023;
    G[idx] = s + bih[c] + bhh[c];
}

// ---------------- K6: LSTM recurrence, one block per batch ----------------
__global__ __launch_bounds__(1024) void k_lstm(const float* __restrict__ G,
                                               const float* __restrict__ whh,
                                               float* __restrict__ hn) {
    int b = blockIdx.x;
    int t = threadIdx.x;
    __shared__ float hs[HH], cs[HH], gb[1024];
    if (t < HH) { hs[t] = 0.f; cs[t] = 0.f; }
    __syncthreads();
    const float4* wrow = (const float4*)(whh + (size_t)t * HH);
    for (int w = 0; w < WW; ++w) {
        float acc = G[(w * BB + b) * 1024 + t];
        const float4* h4 = (const float4*)hs;
#pragma unroll 8
        for (int k4 = 0; k4 < HH / 4; ++k4) {
            float4 wv = wrow[k4];
            float4 hv = h4[k4];
            acc = fmaf(wv.x, hv.x, acc);
            acc = fmaf(wv.y, hv.y, acc);
            acc = fmaf(wv.z, hv.z, acc);
            acc = fmaf(wv.w, hv.w, acc);
        }
        gb[t] = acc;
        __syncthreads();
        if (t < HH) {
            float ig = gb[t], fg = gb[t + 256], gg = gb[t + 512], og = gb[t + 768];
            float si = 1.f / (1.f + __expf(-ig));
            float sf = 1.f / (1.f + __expf(-fg));
            float so = 1.f / (1.f + __expf(-og));
            float cv = sf * cs[t] + si * tanhf(gg);
            float hv = so * tanhf(cv);
            cs[t] = cv;
            hs[t] = hv;
        }
        __syncthreads();
    }
    if (t < HH) hn[b * HH + t] = hs[t];
}

// ---------------- K7: fused f1 GEMV + s1/s2 reduction ----------------
__global__ __launch_bounds__(256) void k_head(const float* __restrict__ hn,
                                              const float* __restrict__ f1w,
                                              const float* __restrict__ f1b,
                                              const float* __restrict__ f2w,
                                              float* __restrict__ s1,
                                              float* __restrict__ s2) {
    __shared__ float h[BB * HH];
    for (int q = threadIdx.x; q < BB * HH; q += 256) h[q] = hn[q];
    __syncthreads();
    int c = blockIdx.x * 256 + threadIdx.x;  // 0..32767
    const float4* wrow = (const float4*)(f1w + (size_t)c * HH);
    const float4* h4   = (const float4*)h;
    float a0 = 0, a1 = 0, a2 = 0, a3 = 0;
#pragma unroll 4
    for (int k4 = 0; k4 < HH / 4; ++k4) {
        float4 wv = wrow[k4];
        float4 h0 = h4[k4];
        float4 h1 = h4[64 + k4];
        float4 h2 = h4[128 + k4];
        float4 h3 = h4[192 + k4];
        a0 = fmaf(wv.x, h0.x, a0); a0 = fmaf(wv.y, h0.y, a0);
        a0 = fmaf(wv.z, h0.z, a0); a0 = fmaf(wv.w, h0.w, a0);
        a1 = fmaf(wv.x, h1.x, a1); a1 = fmaf(wv.y, h1.y, a1);
        a1 = fmaf(wv.z, h1.z, a1); a1 = fmaf(wv.w, h1.w, a1);
        a2 = fmaf(wv.x, h2.x, a2); a2 = fmaf(wv.y, h2.y, a2);
        a2 = fmaf(wv.z, h2.z, a2); a2 = fmaf(wv.w, h2.w, a2);
        a3 = fmaf(wv.x, h3.x, a3); a3 = fmaf(wv.y, h3.y, a3);
        a3 = fmaf(wv.z, h3.z, a3); a3 = fmaf(wv.w, h3.w, a3);
    }
    float bias = f1b[c];
    float o0 = a0 + bias, o1 = a1 + bias, o2 = a2 + bias, o3 = a3 + bias;
    int f = c & 31;
    float w1 = f2w[f], w2 = f2w[32 + f];
    float p0 = o0 * w1, p1 = o1 * w1, p2 = o2 * w1, p3 = o3 * w1;
    float q0 = o0 * w2, q1 = o1 * w2, q2 = o2 * w2, q3 = o3 * w2;
#pragma unroll
    for (int off = 16; off; off >>= 1) {
        p0 += __shfl_xor(p0, off, 64); p1 += __shfl_xor(p1, off, 64);
        p2 += __shfl_xor(p2, off, 64); p3 += __shfl_xor(p3, off, 64);
        q0 += __shfl_xor(q0, off, 64); q1 += __shfl_xor(q1, off, 64);
        q2 += __shfl_xor(q2, off, 64); q3 += __shfl_xor(q3, off, 64);
    }
    if (f == 0) {
        int n = c >> 5;
        s1[0 * NN + n] = p0; s1[1 * NN + n] = p1;
        s1[2 * NN + n] = p2; s1[3 * NN + n] = p3;
        s2[0 * NN + n] = q0; s2[1 * NN + n] = q1;
        s2[2 * NN + n] = q2; s2[3 * NN + n] = q3;
    }
}

// ---------------- K8: scores + keep + L1 normalize ----------------
__global__ __launch_bounds__(256) void k_score(const float* __restrict__ s1,
                                               const float* __restrict__ s2,
                                               const float* __restrict__ f2b,
                                               float* __restrict__ out) {
    int bi = blockIdx.x;  // b*1024 + i
    int b = bi >> 10, i = bi & 1023;
    float fb  = f2b[0];
    float s1i = s1[b * NN + i];
    float s2i = s2[b * NN + i];
    __shared__ float red[4];
    float vals[4];
    float asum = 0.f;
#pragma unroll
    for (int q = 0; q < 4; ++q) {
        int j = q * 256 + threadIdx.x;
        float sc = s1i + s2[b * NN + j] + fb;
        float st = s1[b * NN + j] + s2i + fb;
        bool keep;
        if (i == j)      keep = true;
        else if (i < j)  keep = (sc >= st) && (sc > 0.f);
        else             keep = (sc > st) && (sc >= 0.f);
        float v = keep ? sc : 0.f;
        vals[q] = v;
        asum += fabsf(v);
    }
#pragma unroll
    for (int off = 32; off; off >>= 1) asum += __shfl_xor(asum, off, 64);
    int lane = threadIdx.x & 63, wv = threadIdx.x >> 6;
    if (lane == 0) red[wv] = asum;
    __syncthreads();
    float tot = red[0] + red[1] + red[2] + red[3];
    float inv = 1.f / fmaxf(tot, 1e-12f);
    float* orow = out + (size_t)bi * NN;
#pragma unroll
    for (int q = 0; q < 4; ++q) orow[q * 256 + threadIdx.x] = vals[q] * inv;
}

extern "C" void kernel_launch(void* const* d_in, const int* in_sizes, int n_in,
                              void* d_out, int out_size, void* d_ws, size_t ws_size,
                              hipStream_t stream) {
    const float* in_shots = (const float*)d_in[0];
    const float* in_node  = (const float*)d_in[1];
    // d_in[2] = 'a' (unused by reference)
    const float* gcn_w    = (const float*)d_in[3];
    const float* w_ih     = (const float*)d_in[4];
    const float* w_hh     = (const float*)d_in[5];
    const float* b_ih     = (const float*)d_in[6];
    const float* b_hh     = (const float*)d_in[7];
    const float* f1_w     = (const float*)d_in[8];
    const float* f1_b     = (const float*)d_in[9];
    const float* f2_w     = (const float*)d_in[10];
    const float* f2_b     = (const float*)d_in[11];
    float* out = (float*)d_out;

    float* wsf    = (float*)d_ws;
    float* d_arr  = wsf;                         // 48*1024
    float* tmp2   = wsf + 49152;                 // 48*1024*32
    float* x      = wsf + 49152 + 1572864;       // 12*4*32768
    float* part   = x + 1572864;                 // 64*48*1024
    float* G      = part + NCH * RR * 1024;      // 48*1024
    float* hn     = G + 49152;                   // 4*256
    float* s1     = hn + 1024;                   // 4*1024
    float* s2     = s1 + 4096;                   // 4*1024

    k_rowsum<<<RR * NN / 4, 256, 0, stream>>>(in_shots, d_arr);
    k_tmp2  <<<RR * 128,    256, 0, stream>>>(in_node, gcn_w, d_arr, tmp2);
    k_gcn   <<<RR * 8,      512, 0, stream>>>(in_shots, tmp2, d_arr, x);
    k_proj  <<<4 * NCH,     256, 0, stream>>>(x, w_ih, part);
    k_reduce<<<RR * 1024 / 256, 256, 0, stream>>>(part, b_ih, b_hh, G);
    k_lstm  <<<BB,          1024, 0, stream>>>(G, w_hh, hn);
    k_head  <<<DD / 256,    256, 0, stream>>>(hn, f1_w, f1_b, f2_w, s1, s2);
    k_score <<<BB * NN,     256, 0, stream>>>(s1, s2, f2_b, out);
}